// Round 6
// baseline (162.093 us; speedup 1.0000x reference)
//
#include <hip/hip_runtime.h>

// SE(3) exp + point transform — DMA reads (global_load_lds), nt stores,
// persistent double-buffered waves.
//
// R1/R2/R4 (strided / coalesced-barrier / coalesced-persistent) ALL ran
// ~55 us (2.4 TB/s): lane pattern, barriers, occupancy exonerated. The
// harness fill proves 6.8 TB/s writes. This round changes the READ
// micro-path: HBM->LDS DMA (no VGPR round-trip), fine-grained vmcnt(3)
// (never 0), and nontemporal stores so the 84 MiB output stream stops
// evicting X_v from L3 between chunks.
//
// Chunk = 3 KB = 768 floats = 256 whole points. Per wave: 2 x 3 KB LDS
// double-buffer. Block = 128 (2 waves, 12 KB LDS); grid = 1792 = 7/CU,
// 84 KB LDS -> fully resident, single generation.

#define VMCNT3()    asm volatile("s_waitcnt vmcnt(3)" ::: "memory")
#define VMCNT0()    asm volatile("s_waitcnt vmcnt(0)" ::: "memory")
#define LDS_FENCE() asm volatile("s_waitcnt lgkmcnt(0)" ::: "memory")

typedef float vfloat4 __attribute__((ext_vector_type(4)));  // clang-native, nt-store OK

typedef __attribute__((address_space(3))) void       as3_void;
typedef const __attribute__((address_space(1))) void as1_void;

__device__ __forceinline__ void dma_chunk(const float* gp_lane,  // this lane's 16B slot
                                          float* ldsbase)        // wave-uniform LDS base
{
    // 3 ops x (64 lanes x 16 B) = 3 KB; HW places at ldsbase + lane*16
    __builtin_amdgcn_global_load_lds((as1_void*)(gp_lane),       (as3_void*)(ldsbase),       16, 0, 0);
    __builtin_amdgcn_global_load_lds((as1_void*)(gp_lane + 256), (as3_void*)(ldsbase + 256), 16, 0, 0);
    __builtin_amdgcn_global_load_lds((as1_void*)(gp_lane + 512), (as3_void*)(ldsbase + 512), 16, 0, 0);
}

__global__ __launch_bounds__(128) void se3_apply_kernel(
    const float* __restrict__ X,      // (BT, N, 3) flattened
    const float* __restrict__ dofs,   // (BT, 6)
    float* __restrict__ out,
    int n3)                            // floats per (b,t) = N*3
{
    __shared__ float lds[3072];        // 2 waves x 2 bufs x 768 floats

    const int bt   = blockIdx.x;
    const int lane = threadIdx.x & 63;
    const int w    = threadIdx.x >> 6; // 0..1

    // ---- SE(3) exponential (uniform per block) ----
    const float* d = dofs + bt * 6;
    const float tx = d[0], ty = d[1], tz = d[2];
    const float wx = d[3], wy = d[4], wz = d[5];

    const float nrm2  = wx * wx + wy * wy + wz * wz;
    const float th2   = fmaxf(nrm2, 1e-4f);      // jnp.clip(nrms, 1e-4)
    const float theta = sqrtf(th2);
    const float st = sinf(theta);
    const float ct = cosf(theta);
    const float f1 = st / theta;
    const float f2 = (1.0f - ct) / th2;
    const float f3 = (theta - st) / (th2 * theta);

    const float xx = wx * wx, yy = wy * wy, zz = wz * wz;
    const float xy = wx * wy, xz = wx * wz, yz = wy * wz;

    const float R00 = 1.0f - f2 * (yy + zz);
    const float R01 = f2 * xy - f1 * wz;
    const float R02 = f2 * xz + f1 * wy;
    const float R10 = f2 * xy + f1 * wz;
    const float R11 = 1.0f - f2 * (xx + zz);
    const float R12 = f2 * yz - f1 * wx;
    const float R20 = f2 * xz - f1 * wy;
    const float R21 = f2 * yz + f1 * wx;
    const float R22 = 1.0f - f2 * (xx + yy);

    const float V00 = 1.0f - f3 * (yy + zz);
    const float V01 = f3 * xy - f2 * wz;
    const float V02 = f3 * xz + f2 * wy;
    const float V10 = f3 * xy + f2 * wz;
    const float V11 = 1.0f - f3 * (xx + zz);
    const float V12 = f3 * yz - f2 * wx;
    const float V20 = f3 * xz - f2 * wy;
    const float V21 = f3 * yz + f2 * wx;
    const float V22 = 1.0f - f3 * (xx + yy);

    const float Tx = V00 * tx + V01 * ty + V02 * tz;
    const float Ty = V10 * tx + V11 * ty + V12 * tz;
    const float Tz = V20 * tx + V21 * ty + V22 * tz;

    const long long btBase = (long long)bt * (long long)n3;
    const float* const gX = X + btBase;

    float* const buf0 = lds + w * 1536;
    float* const buf1 = buf0 + 768;

    const int nChunks = n3 / 768;                // 16 for N=4096

    // ---- preload chunk w into buf0 ----
    if (w < nChunks)
        dma_chunk(gX + (long long)w * 768 + lane * 4, buf0);

    for (int c = w, it = 0; c < nChunks; c += 2, ++it) {
        float* const cur = (it & 1) ? buf1 : buf0;
        float* const nxt = (it & 1) ? buf0 : buf1;

        // prefetch chunk c+2 into the other buffer, then drain cur's DMA.
        // vmcnt(3): the 3 newest (prefetch) may stay in flight; everything
        // older (cur's DMA + prior stores) is complete. Never vmcnt(0) on
        // the steady-state path.
        const int cn = c + 2;                    // wave-uniform branch
        if (cn < nChunks) {
            dma_chunk(gX + (long long)cn * 768 + lane * 4, nxt);
            VMCNT3();
        } else {
            VMCNT0();
        }

        // compute in place: 4 points/lane, stride 64 points (conflict-free)
#pragma unroll
        for (int j = 0; j < 4; ++j) {
            const int p = 3 * (lane + 64 * j);
            const float px = cur[p + 0];
            const float py = cur[p + 1];
            const float pz = cur[p + 2];
            cur[p + 0] = fmaf(R00, px, fmaf(R01, py, fmaf(R02, pz, Tx)));
            cur[p + 1] = fmaf(R10, px, fmaf(R11, py, fmaf(R12, pz, Ty)));
            cur[p + 2] = fmaf(R20, px, fmaf(R21, py, fmaf(R22, pz, Tz)));
        }
        LDS_FENCE();                             // results visible to stage-out reads

        // stage-out: lane-contiguous nontemporal 16B stores
        // (nt: don't let the output stream evict X_v from L3)
        vfloat4* const o4 = (vfloat4*)(out + btBase + (long long)c * 768);
        const vfloat4* const c4 = (const vfloat4*)cur;
        __builtin_nontemporal_store(c4[lane],       o4 + lane);
        __builtin_nontemporal_store(c4[lane + 64],  o4 + lane + 64);
        __builtin_nontemporal_store(c4[lane + 128], o4 + lane + 128);
        LDS_FENCE();   // stage-out ds_reads retired before next DMA overwrites this buf
    }

    // ---- tail (n3 % 768; zero for N=4096) ----
    const int nTail = n3 - nChunks * 768;
    if (nTail > 0 && w == 0) {
        const int tailPts = nTail / 3;
        const long long tbase = btBase + (long long)nChunks * 768;
        for (int p = lane; p < tailPts; p += 64) {
            const float px = X[tbase + 3 * p + 0];
            const float py = X[tbase + 3 * p + 1];
            const float pz = X[tbase + 3 * p + 2];
            out[tbase + 3 * p + 0] = fmaf(R00, px, fmaf(R01, py, fmaf(R02, pz, Tx)));
            out[tbase + 3 * p + 1] = fmaf(R10, px, fmaf(R11, py, fmaf(R12, pz, Ty)));
            out[tbase + 3 * p + 2] = fmaf(R20, px, fmaf(R21, py, fmaf(R22, pz, Tz)));
        }
    }
}

extern "C" void kernel_launch(void* const* d_in, const int* in_sizes, int n_in,
                              void* d_out, int out_size, void* d_ws, size_t ws_size,
                              hipStream_t stream) {
    const float* X    = (const float*)d_in[0];
    const float* dofs = (const float*)d_in[1];
    float* out        = (float*)d_out;

    const int BT = in_sizes[1] / 6;            // 64*28 = 1792
    const int n3 = in_sizes[0] / BT;           // 4096*3 = 12288 floats per bt

    dim3 grid((unsigned)BT);                   // 1792 blocks = 7/CU, fully resident
    se3_apply_kernel<<<grid, 128, 0, stream>>>(X, dofs, out, n3);
}